// Round 4
// baseline (403.277 us; speedup 1.0000x reference)
//
#include <hip/hip_runtime.h>

#define SEQ 2048
#define HD 768
#define NBATCH 8

typedef __attribute__((ext_vector_type(4))) float f32x4;
typedef __attribute__((ext_vector_type(8))) short s16x8;

__device__ __forceinline__ unsigned short f2bf(float f) {
  unsigned int u = __builtin_bit_cast(unsigned int, f);
  u += 0x7fffu + ((u >> 16) & 1u);
  return (unsigned short)(u >> 16);
}
__device__ __forceinline__ float bf2f(unsigned short h) {
  unsigned int u = ((unsigned int)h) << 16;
  return __builtin_bit_cast(float, u);
}

typedef const __attribute__((address_space(1))) void gas_void;
typedef __attribute__((address_space(3))) void las_void;

__device__ __forceinline__ void gload_lds16(const void* g, void* l) {
  __builtin_amdgcn_global_load_lds((gas_void*)g, (las_void*)l, 16, 0, 0);
}

// bijective XCD-chunk swizzle; requires nwg % 8 == 0
__device__ __forceinline__ int xcd_swz(int f, int nwg) {
  int q = nwg >> 3;
  return (f & 7) * q + (f >> 3);
}

#define WAITV(N) asm volatile("s_waitcnt vmcnt(" #N ")" ::: "memory")
#define WAITL() asm volatile("s_waitcnt lgkmcnt(0)" ::: "memory")
#define BAR() __builtin_amdgcn_s_barrier()

// ---- 256x256 8-phase GEMM core ---------------------------------------------
// 512 thr = 8 waves (2m x 4n). Wave tile 128x64 = 8x4 frags of 16x16x32.
// m interleaved at 64 (wave's rows: mh*128 + wm*64 + ...), n at 32.
// LDS 128 KB: A halves (128 rows x 64 bf16, XOR-swizzled) at (db*2+h)*16384,
// B at 65536 + same. Half-tile staged per phase via global_load_lds with
// pre-swizzled source (rule #21). Counted vmcnt {6,6,6,4}: loads never drain
// to 0 in the main loop (T3+T4); setprio around MFMA clusters (T5).

__device__ __forceinline__ void stage_half(const unsigned char* g, size_t ldgB,
                                           unsigned char* lds_half, int wid,
                                           int lane) {
#pragma unroll
  for (int c = 0; c < 2; ++c) {
    int i = wid * 2 + c;                             // 0..15, wave-uniform base
    int row = i * 8 + (lane >> 3);
    int cb = (((lane & 7) ^ (lane >> 3)) & 7) << 4;  // inverse-swizzled src col
    gload_lds16(g + (size_t)row * ldgB + cb, lds_half + i * 1024);
  }
}

__device__ __forceinline__ void gemm8_loop(
    const unsigned char* __restrict__ Ag, size_t ldaB,
    const unsigned char* __restrict__ Bg, size_t ldbB, int NT,
    unsigned char* lds, int wid, int lane, int wm, int wn, int lr, int lg,
    f32x4 acc[8][4]) {
  // prologue: tile 0's four halves (A0,B0,A1,B1), wait first two
  stage_half(Ag, ldaB, lds, wid, lane);
  stage_half(Bg, ldbB, lds + 65536, wid, lane);
  stage_half(Ag + 128 * ldaB, ldaB, lds + 16384, wid, lane);
  stage_half(Bg + 128 * ldbB, ldbB, lds + 65536 + 16384, wid, lane);
  WAITV(4);
  BAR();
  int arow = wm * 64 + lr, brow = wn * 32 + lr;
  for (int u = 0; u < NT; ++u) {
    int c = u & 1;
    const unsigned char* A0 = lds + (c * 2 + 0) * 16384;
    const unsigned char* A1 = lds + (c * 2 + 1) * 16384;
    const unsigned char* B0 = lds + 65536 + (c * 2 + 0) * 16384;
    const unsigned char* B1 = lds + 65536 + (c * 2 + 1) * 16384;
    unsigned char* nA0 = lds + ((c ^ 1) * 2 + 0) * 16384;
    unsigned char* nA1 = lds + ((c ^ 1) * 2 + 1) * 16384;
    unsigned char* nB0 = lds + 65536 + ((c ^ 1) * 2 + 0) * 16384;
    unsigned char* nB1 = lds + 65536 + ((c ^ 1) * 2 + 1) * 16384;
    const unsigned char* gA = Ag + (size_t)(u + 1) * 128;
    const unsigned char* gB = Bg + (size_t)(u + 1) * 128;
    bool pf = (u + 1 < NT);
    s16x8 a0[2][4], a1[2][4], b0[2][2], b1[2][2];
    // ----- phase 0: quad (mh=0, nh=0) -- reads A0,B0; stages A0',B0'
#pragma unroll
    for (int ks = 0; ks < 2; ++ks) {
      int kb = ks * 64 + lg * 16;
#pragma unroll
      for (int q = 0; q < 4; ++q) {
        int r = arow + q * 16;
        a0[ks][q] = *(const s16x8*)(A0 + r * 128 + (kb ^ ((r & 7) << 4)));
      }
#pragma unroll
      for (int t = 0; t < 2; ++t) {
        int r = brow + t * 16;
        b0[ks][t] = *(const s16x8*)(B0 + r * 128 + (kb ^ ((r & 7) << 4)));
      }
    }
    if (pf) {
      stage_half(gA, ldaB, nA0, wid, lane);
      stage_half(gB, ldbB, nB0, wid, lane);
      WAITV(6);
    } else {
      WAITV(0);
    }
    BAR();
    WAITL();
    __builtin_amdgcn_s_setprio(1);
#pragma unroll
    for (int ks = 0; ks < 2; ++ks)
#pragma unroll
      for (int q = 0; q < 4; ++q)
#pragma unroll
        for (int t = 0; t < 2; ++t)
          acc[q][t] = __builtin_amdgcn_mfma_f32_16x16x32_bf16(
              a0[ks][q], b0[ks][t], acc[q][t], 0, 0, 0);
    __builtin_amdgcn_s_setprio(0);
    BAR();
    // ----- phase 1: quad (1,0) -- reads A1 (reuse b0); stages A1'
#pragma unroll
    for (int ks = 0; ks < 2; ++ks) {
      int kb = ks * 64 + lg * 16;
#pragma unroll
      for (int q = 0; q < 4; ++q) {
        int r = arow + q * 16;
        a1[ks][q] = *(const s16x8*)(A1 + r * 128 + (kb ^ ((r & 7) << 4)));
      }
    }
    if (pf) {
      stage_half(gA + 128 * ldaB, ldaB, nA1, wid, lane);
      WAITV(6);
    } else {
      WAITV(0);
    }
    BAR();
    WAITL();
    __builtin_amdgcn_s_setprio(1);
#pragma unroll
    for (int ks = 0; ks < 2; ++ks)
#pragma unroll
      for (int q = 0; q < 4; ++q)
#pragma unroll
        for (int t = 0; t < 2; ++t)
          acc[4 + q][t] = __builtin_amdgcn_mfma_f32_16x16x32_bf16(
              a1[ks][q], b0[ks][t], acc[4 + q][t], 0, 0, 0);
    __builtin_amdgcn_s_setprio(0);
    BAR();
    // ----- phase 2: quad (1,1) -- reads B1 (reuse a1); stages B1'
#pragma unroll
    for (int ks = 0; ks < 2; ++ks) {
      int kb = ks * 64 + lg * 16;
#pragma unroll
      for (int t = 0; t < 2; ++t) {
        int r = brow + t * 16;
        b1[ks][t] = *(const s16x8*)(B1 + r * 128 + (kb ^ ((r & 7) << 4)));
      }
    }
    if (pf) {
      stage_half(gB + 128 * ldbB, ldbB, nB1, wid, lane);
      WAITV(6);
    }
    BAR();
    WAITL();
    __builtin_amdgcn_s_setprio(1);
#pragma unroll
    for (int ks = 0; ks < 2; ++ks)
#pragma unroll
      for (int q = 0; q < 4; ++q)
#pragma unroll
        for (int t = 0; t < 2; ++t)
          acc[4 + q][2 + t] = __builtin_amdgcn_mfma_f32_16x16x32_bf16(
              a1[ks][q], b1[ks][t], acc[4 + q][2 + t], 0, 0, 0);
    __builtin_amdgcn_s_setprio(0);
    BAR();
    // ----- phase 3: quad (0,1) -- no reads (reuse a0,b1); no stage
    if (pf) WAITV(4);
    BAR();
    __builtin_amdgcn_s_setprio(1);
#pragma unroll
    for (int ks = 0; ks < 2; ++ks)
#pragma unroll
      for (int q = 0; q < 4; ++q)
#pragma unroll
        for (int t = 0; t < 2; ++t)
          acc[q][2 + t] = __builtin_amdgcn_mfma_f32_16x16x32_bf16(
              a0[ks][q], b1[ks][t], acc[q][2 + t], 0, 0, 0);
    __builtin_amdgcn_s_setprio(0);
    BAR();
  }
}

#define G8_PROLOGUE()                                               \
  __shared__ unsigned char lds[131072];                             \
  int tid = threadIdx.x, lane = tid & 63, wid = tid >> 6;           \
  int wm = wid >> 2, wn = wid & 3, lr = lane & 15, lg = lane >> 4;  \
  f32x4 acc[8][4];                                                  \
  {                                                                 \
    f32x4 zz = {0.f, 0.f, 0.f, 0.f};                                \
    for (int a_ = 0; a_ < 8; ++a_)                                  \
      for (int b_ = 0; b_ < 4; ++b_) acc[a_][b_] = zz;              \
  }                                                                 \
  (void)tid;

// epilogue index helpers: C row/col within the 256x256 block tile
#define CROW(mi, j) (((mi) >> 2) * 128 + wm * 64 + ((mi)&3) * 16 + lg * 4 + (j))
#define CCOL(ni) ((((ni) >> 1) * 128 + wn * 32 + ((ni)&1) * 16 + lr))

// ---- prep: LDS-tiled weight transpose+convert  Wt[n][k] = bf16(W[k][n]) ----
__global__ __launch_bounds__(256) void prep_weights(
    const float* __restrict__ Wq, const float* __restrict__ Wk,
    const float* __restrict__ Wv, const float* __restrict__ Wo,
    unsigned short* __restrict__ Wt) {
  int mat = blockIdx.z;
  const float* W = mat == 0 ? Wq : mat == 1 ? Wk : mat == 2 ? Wv : Wo;
  unsigned short* dst = Wt + (size_t)mat * HD * HD;
  int n0 = blockIdx.x * 64, k0 = blockIdx.y * 64;
  __shared__ float t[64][65];
  int tid = threadIdx.x;
  int c4 = (tid & 15) * 4, r = tid >> 4;
#pragma unroll
  for (int p = 0; p < 4; ++p) {
    int kr = r + p * 16;
    float4 v = *(const float4*)(W + (size_t)(k0 + kr) * HD + n0 + c4);
    t[kr][c4 + 0] = v.x; t[kr][c4 + 1] = v.y;
    t[kr][c4 + 2] = v.z; t[kr][c4 + 3] = v.w;
  }
  __syncthreads();
#pragma unroll
  for (int p = 0; p < 4; ++p) {
    int nr = r + p * 16;
    ushort4 o;
    o.x = f2bf(t[c4 + 0][nr]); o.y = f2bf(t[c4 + 1][nr]);
    o.z = f2bf(t[c4 + 2][nr]); o.w = f2bf(t[c4 + 3][nr]);
    *(ushort4*)(dst + (size_t)(n0 + nr) * HD + k0 + c4) = o;
  }
}

// ---- prep: X f32 -> bf16 ----------------------------------------------------
__global__ __launch_bounds__(256) void prep_x(const float* __restrict__ X,
                                              unsigned short* __restrict__ Xb) {
  size_t i = ((size_t)blockIdx.x * 256 + threadIdx.x) * 8;
  const float4* gp = (const float4*)(X + i);
  float4 a = gp[0], b = gp[1];
  s16x8 v;
  v[0] = (short)f2bf(a.x); v[1] = (short)f2bf(a.y);
  v[2] = (short)f2bf(a.z); v[3] = (short)f2bf(a.w);
  v[4] = (short)f2bf(b.x); v[5] = (short)f2bf(b.y);
  v[6] = (short)f2bf(b.z); v[7] = (short)f2bf(b.w);
  *(s16x8*)(Xb + i) = v;
}

// ---- QKV projection (z: 0=Q,1=K,2=V-transposed) ----------------------------
__global__ __launch_bounds__(512, 2) void qkv_gemm(
    const unsigned short* __restrict__ Xb, const unsigned short* __restrict__ Wt,
    const float* __restrict__ bq, const float* __restrict__ bk,
    const float* __restrict__ bv, unsigned short* __restrict__ Q,
    unsigned short* __restrict__ K, unsigned short* __restrict__ Vt) {
  int which = blockIdx.z;
  const unsigned short* W = Wt + (size_t)which * HD * HD;
  const float* bias = which == 0 ? bq : which == 1 ? bk : bv;
  int f = xcd_swz(blockIdx.x + 3 * blockIdx.y, 3 * (NBATCH * SEQ / 256));
  int n0 = (f % 3) * 256, m0 = (f / 3) * 256;
  G8_PROLOGUE();
  gemm8_loop((const unsigned char*)(Xb + (size_t)m0 * HD), HD * 2,
             (const unsigned char*)(W + (size_t)n0 * HD), HD * 2, HD / 64, lds,
             wid, lane, wm, wn, lr, lg, acc);
  if (which < 2) {
    unsigned short* out = which == 0 ? Q : K;
#pragma unroll
    for (int mi = 0; mi < 8; ++mi)
#pragma unroll
      for (int ni = 0; ni < 4; ++ni) {
        int col = n0 + CCOL(ni);
        float bb = bias[col];
#pragma unroll
        for (int j = 0; j < 4; ++j) {
          int row = m0 + CROW(mi, j);
          out[(size_t)row * HD + col] = f2bf(acc[mi][ni][j] + bb);
        }
      }
  } else {
#pragma unroll
    for (int mi = 0; mi < 8; ++mi)
#pragma unroll
      for (int ni = 0; ni < 4; ++ni) {
        int col = n0 + CCOL(ni);
        float bb = bias[col];
#pragma unroll
        for (int j = 0; j < 4; ++j) {
          int row = m0 + CROW(mi, j);
          int b = row >> 11, s = row & (SEQ - 1);
          Vt[(size_t)b * HD * SEQ + (size_t)col * SEQ + s] =
              f2bf(acc[mi][ni][j] + bb);
        }
      }
  }
}

// ---- scores = scale * Q @ K^T ----------------------------------------------
__global__ __launch_bounds__(512, 2) void scores_gemm(
    const unsigned short* __restrict__ Q, const unsigned short* __restrict__ K,
    unsigned short* __restrict__ S, int b0) {
  int z = blockIdx.z, batch = b0 + z;
  const unsigned char* Qb = (const unsigned char*)(Q + (size_t)batch * SEQ * HD);
  const unsigned char* Kb = (const unsigned char*)(K + (size_t)batch * SEQ * HD);
  unsigned short* Sout = S + (size_t)z * SEQ * SEQ;
  int f = xcd_swz(blockIdx.x + 8 * blockIdx.y, 64);
  int n0 = (f % 8) * 256, m0 = (f / 8) * 256;
  G8_PROLOGUE();
  gemm8_loop(Qb + (size_t)m0 * HD * 2, HD * 2, Kb + (size_t)n0 * HD * 2, HD * 2,
             HD / 64, lds, wid, lane, wm, wn, lr, lg, acc);
  const float scale = 0.036084391824351615f;  // 1/sqrt(768)
#pragma unroll
  for (int mi = 0; mi < 8; ++mi)
#pragma unroll
    for (int ni = 0; ni < 4; ++ni) {
      int col = n0 + CCOL(ni);
#pragma unroll
      for (int j = 0; j < 4; ++j) {
        int row = m0 + CROW(mi, j);
        Sout[(size_t)row * SEQ + col] = f2bf(acc[mi][ni][j] * scale);
      }
    }
}

// ---- masked softmax over key dim, in place on S ----------------------------
__global__ __launch_bounds__(256) void softmax_kernel(
    unsigned short* __restrict__ S, const int* __restrict__ mask, int b0) {
  int z = blockIdx.y, batch = b0 + z;
  int r = blockIdx.x;
  unsigned short* row = S + ((size_t)z * SEQ + r) * SEQ;
  const int* mrow = mask + (size_t)batch * SEQ;
  int tid = threadIdx.x, lane = tid & 63, wid = tid >> 6;
  int t0 = tid * 8;
  s16x8 sv = *(const s16x8*)(row + t0);
  int4 ma = *(const int4*)(mrow + t0);
  int4 mb = *(const int4*)(mrow + t0 + 4);
  int mk[8] = {ma.x, ma.y, ma.z, ma.w, mb.x, mb.y, mb.z, mb.w};
  float v[8];
  float mx = -1e30f;
#pragma unroll
  for (int j = 0; j < 8; ++j) {
    float x = bf2f((unsigned short)sv[j]);
    v[j] = mk[j] ? x : -1e30f;
    mx = fmaxf(mx, v[j]);
  }
#pragma unroll
  for (int o = 32; o; o >>= 1) mx = fmaxf(mx, __shfl_xor(mx, o));
  __shared__ float red[8];
  if (lane == 0) red[wid] = mx;
  __syncthreads();
  mx = fmaxf(fmaxf(red[0], red[1]), fmaxf(red[2], red[3]));
  float sum = 0.f;
  float e[8];
#pragma unroll
  for (int j = 0; j < 8; ++j) {
    e[j] = mk[j] ? __expf(v[j] - mx) : 0.f;
    sum += e[j];
  }
#pragma unroll
  for (int o = 32; o; o >>= 1) sum += __shfl_xor(sum, o);
  if (lane == 0) red[4 + wid] = sum;
  __syncthreads();
  sum = red[4] + red[5] + red[6] + red[7];
  float inv = sum > 0.f ? 1.f / sum : 0.f;
  s16x8 pv;
#pragma unroll
  for (int j = 0; j < 8; ++j) pv[j] = (short)f2bf(e[j] * inv);
  *(s16x8*)(row + t0) = pv;
}

// ---- ctx = P @ V  (B staged from V-transposed) -----------------------------
__global__ __launch_bounds__(512, 2) void pv_gemm(
    const unsigned short* __restrict__ P, const unsigned short* __restrict__ Vt,
    unsigned short* __restrict__ ctx, int b0) {
  int z = blockIdx.z, batch = b0 + z;
  const unsigned char* Pb = (const unsigned char*)(P + (size_t)z * SEQ * SEQ);
  const unsigned char* Vb = (const unsigned char*)(Vt + (size_t)batch * HD * SEQ);
  int f = xcd_swz(blockIdx.x + 3 * blockIdx.y, 3 * (SEQ / 256));
  int n0 = (f % 3) * 256, m0 = (f / 3) * 256;
  G8_PROLOGUE();
  gemm8_loop(Pb + (size_t)m0 * SEQ * 2, SEQ * 2, Vb + (size_t)n0 * SEQ * 2,
             SEQ * 2, SEQ / 64, lds, wid, lane, wm, wn, lr, lg, acc);
#pragma unroll
  for (int mi = 0; mi < 8; ++mi)
#pragma unroll
    for (int ni = 0; ni < 4; ++ni) {
      int col = n0 + CCOL(ni);
#pragma unroll
      for (int j = 0; j < 4; ++j) {
        int row = m0 + CROW(mi, j);
        ctx[((size_t)batch * SEQ + row) * HD + col] = f2bf(acc[mi][ni][j]);
      }
    }
}

// ---- h = ctx @ Wo + bo + X  (f32 to d_out) ---------------------------------
__global__ __launch_bounds__(512, 2) void outproj_gemm(
    const unsigned short* __restrict__ ctx, const unsigned short* __restrict__ Wto,
    const float* __restrict__ bo, const float* __restrict__ X,
    float* __restrict__ out) {
  int f = xcd_swz(blockIdx.x + 3 * blockIdx.y, 3 * (NBATCH * SEQ / 256));
  int n0 = (f % 3) * 256, m0 = (f / 3) * 256;
  G8_PROLOGUE();
  gemm8_loop((const unsigned char*)(ctx + (size_t)m0 * HD), HD * 2,
             (const unsigned char*)(Wto + (size_t)n0 * HD), HD * 2, HD / 64,
             lds, wid, lane, wm, wn, lr, lg, acc);
#pragma unroll
  for (int mi = 0; mi < 8; ++mi)
#pragma unroll
    for (int ni = 0; ni < 4; ++ni) {
      int col = n0 + CCOL(ni);
      float bb = bo[col];
#pragma unroll
      for (int j = 0; j < 4; ++j) {
        int row = m0 + CROW(mi, j);
        size_t idx = (size_t)row * HD + col;
        out[idx] = acc[mi][ni][j] + bb + X[idx];
      }
    }
}

// ---- LayerNorm in place on d_out -------------------------------------------
__global__ __launch_bounds__(256) void ln_kernel(float* __restrict__ out,
                                                 const float* __restrict__ gamma,
                                                 const float* __restrict__ beta) {
  int r = blockIdx.x;
  float* row = out + (size_t)r * HD;
  int tid = threadIdx.x, lane = tid & 63, wid = tid >> 6;
  float4 x = {0.f, 0.f, 0.f, 0.f};
  if (tid < 192) x = *(const float4*)(row + tid * 4);
  float s = x.x + x.y + x.z + x.w;
  float q = x.x * x.x + x.y * x.y + x.z * x.z + x.w * x.w;
#pragma unroll
  for (int o = 32; o; o >>= 1) {
    s += __shfl_xor(s, o);
    q += __shfl_xor(q, o);
  }
  __shared__ float red[8];
  if (lane == 0) { red[wid] = s; red[4 + wid] = q; }
  __syncthreads();
  s = red[0] + red[1] + red[2] + red[3];
  q = red[4] + red[5] + red[6] + red[7];
  float mu = s * (1.f / 768.f);
  float var = q * (1.f / 768.f) - mu * mu;
  float rstd = rsqrtf(var + 1e-12f);
  if (tid < 192) {
    float4 g = *(const float4*)(gamma + tid * 4);
    float4 b = *(const float4*)(beta + tid * 4);
    float4 y;
    y.x = (x.x - mu) * rstd * g.x + b.x;
    y.y = (x.y - mu) * rstd * g.y + b.y;
    y.z = (x.z - mu) * rstd * g.z + b.z;
    y.w = (x.w - mu) * rstd * g.w + b.w;
    *(float4*)(row + tid * 4) = y;
  }
}

// ---- host ------------------------------------------------------------------
extern "C" void kernel_launch(void* const* d_in, const int* in_sizes, int n_in,
                              void* d_out, int out_size, void* d_ws, size_t ws_size,
                              hipStream_t stream) {
  const float* X = (const float*)d_in[0];
  const int* mask = (const int*)d_in[1];
  const float* Wq = (const float*)d_in[2];
  const float* bq = (const float*)d_in[3];
  const float* Wk = (const float*)d_in[4];
  const float* bk = (const float*)d_in[5];
  const float* Wv = (const float*)d_in[6];
  const float* bv = (const float*)d_in[7];
  const float* Wo = (const float*)d_in[8];
  const float* bo = (const float*)d_in[9];
  const float* gamma = (const float*)d_in[10];
  const float* beta = (const float*)d_in[11];
  float* out = (float*)d_out;

  char* ws = (char*)d_ws;
  size_t off = 0;
  auto alloc = [&](size_t b) {
    void* p = ws + off;
    off += (b + 255) & ~(size_t)255;
    return p;
  };
  unsigned short* Wt = (unsigned short*)alloc((size_t)4 * HD * HD * 2);
  unsigned short* Xb = (unsigned short*)alloc((size_t)NBATCH * SEQ * HD * 2);
  unsigned short* Q = (unsigned short*)alloc((size_t)NBATCH * SEQ * HD * 2);
  unsigned short* K = (unsigned short*)alloc((size_t)NBATCH * SEQ * HD * 2);
  unsigned short* Vt = (unsigned short*)alloc((size_t)NBATCH * SEQ * HD * 2);
  int nchunk = (ws_size >= off + (size_t)NBATCH * SEQ * SEQ * 2) ? NBATCH : 1;
  unsigned short* Sbuf = (unsigned short*)alloc((size_t)nchunk * SEQ * SEQ * 2);
  unsigned short* ctx = Q;  // Q dead once scores are computed

  prep_weights<<<dim3(HD / 64, HD / 64, 4), 256, 0, stream>>>(Wq, Wk, Wv, Wo, Wt);
  prep_x<<<(NBATCH * SEQ * HD) / (256 * 8), 256, 0, stream>>>(X, Xb);
  qkv_gemm<<<dim3(HD / 256, NBATCH * SEQ / 256, 3), 512, 0, stream>>>(
      Xb, Wt, bq, bk, bv, Q, K, Vt);
  for (int b0 = 0; b0 < NBATCH; b0 += nchunk) {
    scores_gemm<<<dim3(SEQ / 256, SEQ / 256, nchunk), 512, 0, stream>>>(Q, K, Sbuf, b0);
    softmax_kernel<<<dim3(SEQ, nchunk), 256, 0, stream>>>(Sbuf, mask, b0);
    pv_gemm<<<dim3(HD / 256, SEQ / 256, nchunk), 512, 0, stream>>>(Sbuf, Vt, ctx, b0);
  }
  outproj_gemm<<<dim3(HD / 256, NBATCH * SEQ / 256), 512, 0, stream>>>(
      ctx, Wt + (size_t)3 * HD * HD, bo, X, out);
  ln_kernel<<<NBATCH * SEQ, 256, 0, stream>>>(out, gamma, beta);
}

// Round 5
// 346.929 us; speedup vs baseline: 1.1624x; 1.1624x over previous
//
#include <hip/hip_runtime.h>

#define SEQ 2048
#define HD 768
#define NBATCH 8

typedef __attribute__((ext_vector_type(4))) float f32x4;
typedef __attribute__((ext_vector_type(8))) short s16x8;

__device__ __forceinline__ unsigned short f2bf(float f) {
  unsigned int u = __builtin_bit_cast(unsigned int, f);
  u += 0x7fffu + ((u >> 16) & 1u);
  return (unsigned short)(u >> 16);
}
__device__ __forceinline__ float bf2f(unsigned short h) {
  unsigned int u = ((unsigned int)h) << 16;
  return __builtin_bit_cast(float, u);
}

typedef const __attribute__((address_space(1))) void gas_void;
typedef __attribute__((address_space(3))) void las_void;

__device__ __forceinline__ void gload_lds16(const void* g, void* l) {
  __builtin_amdgcn_global_load_lds((gas_void*)g, (las_void*)l, 16, 0, 0);
}

// bijective XCD-chunk swizzle; requires nwg % 8 == 0
__device__ __forceinline__ int xcd_swz(int f, int nwg) {
  int q = nwg >> 3;
  return (f & 7) * q + (f >> 3);
}

// ---- GEMM building blocks (verified R3 128x128 structure) ------------------
// LDS tile: 128 rows x 64 bf16 cols (128 B/row), XOR-swizzled:
//   phys = row*128 + (cb ^ ((row&7)<<4)); staging pre-swizzles the global
//   SOURCE column so global_load_lds' linear dest lands correctly (rule #21).

__device__ __forceinline__ void stage_b16(const unsigned char* g, size_t ldgB,
                                          unsigned char* lds, int wid, int lane) {
#pragma unroll
  for (int c = 0; c < 4; ++c) {
    int f0 = (wid * 4 + c) * 1024;                  // wave-uniform LDS base
    int row = (f0 >> 7) + (lane >> 3);              // 8 rows per 1024B call
    int cb = (((lane & 7) ^ (lane >> 3)) & 7) << 4; // inverse-swizzled src col
    gload_lds16(g + (size_t)row * ldgB + cb, lds + f0);
  }
}

// 4 waves, wave (wr,wc) owns 64x64; 4x4 frags of 16x16, BK=64 (2 k-substeps)
__device__ __forceinline__ void tile_mfma(const unsigned char* ldsA,
                                          const unsigned char* ldsB,
                                          int wr, int wc, int lr, int lg,
                                          f32x4 acc[4][4]) {
  int aswz = (lr & 7) << 4;
#pragma unroll
  for (int ks = 0; ks < 2; ++ks) {
    int cb = (ks * 64 + lg * 16) ^ aswz;
    s16x8 af[4], bfv[4];
#pragma unroll
    for (int i = 0; i < 4; ++i)
      af[i] = *(const s16x8*)(ldsA + (wr * 64 + i * 16 + lr) * 128 + cb);
#pragma unroll
    for (int i = 0; i < 4; ++i)
      bfv[i] = *(const s16x8*)(ldsB + (wc * 64 + i * 16 + lr) * 128 + cb);
#pragma unroll
    for (int mi = 0; mi < 4; ++mi)
#pragma unroll
      for (int ni = 0; ni < 4; ++ni)
        acc[mi][ni] = __builtin_amdgcn_mfma_f32_16x16x32_bf16(
            af[mi], bfv[ni], acc[mi][ni], 0, 0, 0);
  }
}

#define GEMM_PROLOGUE()                                              \
  __shared__ unsigned char lds[32768];                               \
  unsigned char* ldsA = lds;                                         \
  unsigned char* ldsB = lds + 16384;                                 \
  int tid = threadIdx.x, lane = tid & 63, wid = tid >> 6;            \
  int lr = lane & 15, lg = lane >> 4, wr = wid >> 1, wc = wid & 1;   \
  f32x4 acc[4][4];                                                   \
  {                                                                  \
    f32x4 zz = {0.f, 0.f, 0.f, 0.f};                                 \
    for (int a_ = 0; a_ < 4; ++a_)                                   \
      for (int b_ = 0; b_ < 4; ++b_) acc[a_][b_] = zz;               \
  }                                                                  \
  (void)tid;

// ---- zero fill (for compacted K/V pad regions) -----------------------------
__global__ __launch_bounds__(256) void zero_fill(s16x8* __restrict__ p) {
  size_t i = (size_t)blockIdx.x * 256 + threadIdx.x;
  s16x8 z = {0, 0, 0, 0, 0, 0, 0, 0};
  p[i] = z;
}

// ---- mask compaction: cidx[b][s] = slot or -1; counts[b] = #kept -----------
__global__ __launch_bounds__(256) void compact_mask(const int* __restrict__ mask,
                                                    int* __restrict__ cidx,
                                                    int* __restrict__ counts) {
  int b = blockIdx.x;
  const int* m = mask + (size_t)b * SEQ;
  int* ci = cidx + (size_t)b * SEQ;
  int tid = threadIdx.x, lane = tid & 63, wid = tid >> 6;
  int t0 = tid * 8;
  int4 a = *(const int4*)(m + t0);
  int4 c = *(const int4*)(m + t0 + 4);
  int mk[8] = {a.x, a.y, a.z, a.w, c.x, c.y, c.z, c.w};
  int psum[8], s = 0;
#pragma unroll
  for (int j = 0; j < 8; ++j) {
    psum[j] = s;
    s += (mk[j] != 0);
  }
  int incl = s;
  for (int o = 1; o < 64; o <<= 1) {
    int t = __shfl_up(incl, o);
    if (lane >= o) incl += t;
  }
  int wexcl = incl - s;
  __shared__ int wtot[4];
  if (lane == 63) wtot[wid] = incl;
  __syncthreads();
  int woff = 0;
#pragma unroll
  for (int w2 = 0; w2 < 4; ++w2)
    if (w2 < wid) woff += wtot[w2];
  int base = woff + wexcl;
#pragma unroll
  for (int j = 0; j < 8; ++j)
    ci[t0 + j] = mk[j] ? (base + psum[j]) : -1;
  if (tid == 255) counts[b] = woff + incl;
}

// ---- prep: LDS-tiled weight transpose+convert  Wt[n][k] = bf16(W[k][n]) ----
__global__ __launch_bounds__(256) void prep_weights(
    const float* __restrict__ Wq, const float* __restrict__ Wk,
    const float* __restrict__ Wv, const float* __restrict__ Wo,
    unsigned short* __restrict__ Wt) {
  int mat = blockIdx.z;
  const float* W = mat == 0 ? Wq : mat == 1 ? Wk : mat == 2 ? Wv : Wo;
  unsigned short* dst = Wt + (size_t)mat * HD * HD;
  int n0 = blockIdx.x * 64, k0 = blockIdx.y * 64;
  __shared__ float t[64][65];
  int tid = threadIdx.x;
  int c4 = (tid & 15) * 4, r = tid >> 4;
#pragma unroll
  for (int p = 0; p < 4; ++p) {
    int kr = r + p * 16;
    float4 v = *(const float4*)(W + (size_t)(k0 + kr) * HD + n0 + c4);
    t[kr][c4 + 0] = v.x; t[kr][c4 + 1] = v.y;
    t[kr][c4 + 2] = v.z; t[kr][c4 + 3] = v.w;
  }
  __syncthreads();
#pragma unroll
  for (int p = 0; p < 4; ++p) {
    int nr = r + p * 16;
    ushort4 o;
    o.x = f2bf(t[c4 + 0][nr]); o.y = f2bf(t[c4 + 1][nr]);
    o.z = f2bf(t[c4 + 2][nr]); o.w = f2bf(t[c4 + 3][nr]);
    *(ushort4*)(dst + (size_t)(n0 + nr) * HD + k0 + c4) = o;
  }
}

// ---- prep: X f32 -> bf16 ----------------------------------------------------
__global__ __launch_bounds__(256) void prep_x(const float* __restrict__ X,
                                              unsigned short* __restrict__ Xb) {
  size_t i = ((size_t)blockIdx.x * 256 + threadIdx.x) * 8;
  const float4* gp = (const float4*)(X + i);
  float4 a = gp[0], b = gp[1];
  s16x8 v;
  v[0] = (short)f2bf(a.x); v[1] = (short)f2bf(a.y);
  v[2] = (short)f2bf(a.z); v[3] = (short)f2bf(a.w);
  v[4] = (short)f2bf(b.x); v[5] = (short)f2bf(b.y);
  v[6] = (short)f2bf(b.z); v[7] = (short)f2bf(b.w);
  *(s16x8*)(Xb + i) = v;
}

// ---- QKV projection (z: 0=Q, 1=K-compacted, 2=V-transposed-compacted) ------
__global__ __launch_bounds__(256, 4) void qkv_gemm(
    const unsigned short* __restrict__ Xb, const unsigned short* __restrict__ Wt,
    const float* __restrict__ bq, const float* __restrict__ bk,
    const float* __restrict__ bv, const int* __restrict__ cidx,
    unsigned short* __restrict__ Q, unsigned short* __restrict__ Kc,
    unsigned short* __restrict__ Vtc) {
  int which = blockIdx.z;
  const unsigned short* W = Wt + (size_t)which * HD * HD;
  const float* bias = which == 0 ? bq : which == 1 ? bk : bv;
  int f = xcd_swz(blockIdx.x + 6 * blockIdx.y, 6 * (NBATCH * SEQ / 128));
  int n0 = (f % 6) * 128, m0 = (f / 6) * 128;
  GEMM_PROLOGUE();
  for (int kt = 0; kt < HD / 64; ++kt) {
    stage_b16((const unsigned char*)Xb + ((size_t)m0 * HD + kt * 64) * 2,
              HD * 2, ldsA, wid, lane);
    stage_b16((const unsigned char*)W + ((size_t)n0 * HD + kt * 64) * 2,
              HD * 2, ldsB, wid, lane);
    __syncthreads();
    tile_mfma(ldsA, ldsB, wr, wc, lr, lg, acc);
    __syncthreads();
  }
  if (which == 0) {
#pragma unroll
    for (int mi = 0; mi < 4; ++mi)
#pragma unroll
      for (int ni = 0; ni < 4; ++ni) {
        int col = n0 + wc * 64 + ni * 16 + lr;
        float bb = bias[col];
#pragma unroll
        for (int j = 0; j < 4; ++j) {
          int row = m0 + wr * 64 + mi * 16 + lg * 4 + j;
          Q[(size_t)row * HD + col] = f2bf(acc[mi][ni][j] + bb);
        }
      }
  } else if (which == 1) {
    // K scattered into compacted slots
#pragma unroll
    for (int mi = 0; mi < 4; ++mi) {
      int slot[4];
#pragma unroll
      for (int j = 0; j < 4; ++j) {
        int row = m0 + wr * 64 + mi * 16 + lg * 4 + j;
        slot[j] = cidx[row];  // row = b*2048+s, cidx flat over b,s
      }
#pragma unroll
      for (int ni = 0; ni < 4; ++ni) {
        int col = n0 + wc * 64 + ni * 16 + lr;
        float bb = bias[col];
#pragma unroll
        for (int j = 0; j < 4; ++j) {
          if (slot[j] >= 0) {
            int row = m0 + wr * 64 + mi * 16 + lg * 4 + j;
            int b = row >> 11;
            Kc[((size_t)b * SEQ + slot[j]) * HD + col] =
                f2bf(acc[mi][ni][j] + bb);
          }
        }
      }
    }
  } else {
    // V transposed + compacted: Vtc[b][col][slot]
#pragma unroll
    for (int mi = 0; mi < 4; ++mi) {
      int slot[4];
#pragma unroll
      for (int j = 0; j < 4; ++j) {
        int row = m0 + wr * 64 + mi * 16 + lg * 4 + j;
        slot[j] = cidx[row];
      }
#pragma unroll
      for (int ni = 0; ni < 4; ++ni) {
        int col = n0 + wc * 64 + ni * 16 + lr;
        float bb = bias[col];
#pragma unroll
        for (int j = 0; j < 4; ++j) {
          if (slot[j] >= 0) {
            int row = m0 + wr * 64 + mi * 16 + lg * 4 + j;
            int b = row >> 11;
            Vtc[(size_t)b * HD * SEQ + (size_t)col * SEQ + slot[j]] =
                f2bf(acc[mi][ni][j] + bb);
          }
        }
      }
    }
  }
}

// ---- scores = scale * Q @ Kc^T  (compacted key dim, bf16 out) --------------
__global__ __launch_bounds__(256, 4) void scores_gemm(
    const unsigned short* __restrict__ Q, const unsigned short* __restrict__ Kc,
    const int* __restrict__ counts, unsigned short* __restrict__ S, int b0) {
  int z = blockIdx.z, batch = b0 + z;
  int count = counts[batch];
  int f = xcd_swz(blockIdx.x + 16 * blockIdx.y, 256);
  int n0 = (f % 16) * 128, m0 = (f / 16) * 128;
  if (n0 >= count) return;  // whole block masked out (uniform exit)
  const unsigned char* Qb = (const unsigned char*)(Q + (size_t)batch * SEQ * HD);
  const unsigned char* Kb = (const unsigned char*)(Kc + (size_t)batch * SEQ * HD);
  unsigned short* Sout = S + (size_t)z * SEQ * SEQ;
  GEMM_PROLOGUE();
  for (int kt = 0; kt < HD / 64; ++kt) {
    stage_b16(Qb + ((size_t)m0 * HD + kt * 64) * 2, HD * 2, ldsA, wid, lane);
    stage_b16(Kb + ((size_t)n0 * HD + kt * 64) * 2, HD * 2, ldsB, wid, lane);
    __syncthreads();
    tile_mfma(ldsA, ldsB, wr, wc, lr, lg, acc);
    __syncthreads();
  }
  const float scale = 0.036084391824351615f;  // 1/sqrt(768)
#pragma unroll
  for (int mi = 0; mi < 4; ++mi)
#pragma unroll
    for (int ni = 0; ni < 4; ++ni) {
      int col = n0 + wc * 64 + ni * 16 + lr;
#pragma unroll
      for (int j = 0; j < 4; ++j) {
        int row = m0 + wr * 64 + mi * 16 + lg * 4 + j;
        Sout[(size_t)row * SEQ + col] = f2bf(acc[mi][ni][j] * scale);
      }
    }
}

// ---- softmax over compacted key dim, in place on S -------------------------
__global__ __launch_bounds__(256) void softmax_kernel(
    unsigned short* __restrict__ S, const int* __restrict__ counts, int b0) {
  int z = blockIdx.y, batch = b0 + z;
  int count = counts[batch];
  int nt64 = ((count + 63) >> 6) << 6;  // width pv will consume
  int r = blockIdx.x;
  unsigned short* row = S + ((size_t)z * SEQ + r) * SEQ;
  int tid = threadIdx.x, lane = tid & 63, wid = tid >> 6;
  int t0 = tid * 8;
  bool act = t0 < nt64;
  s16x8 sv = {0, 0, 0, 0, 0, 0, 0, 0};
  if (act) sv = *(const s16x8*)(row + t0);
  float v[8];
  float mx = -1e30f;
#pragma unroll
  for (int j = 0; j < 8; ++j) {
    float x = bf2f((unsigned short)sv[j]);
    bool keep = act && (t0 + j < count);
    v[j] = keep ? x : -1e30f;
    mx = fmaxf(mx, v[j]);
  }
#pragma unroll
  for (int o = 32; o; o >>= 1) mx = fmaxf(mx, __shfl_xor(mx, o));
  __shared__ float red[8];
  if (lane == 0) red[wid] = mx;
  __syncthreads();
  mx = fmaxf(fmaxf(red[0], red[1]), fmaxf(red[2], red[3]));
  float sum = 0.f;
  float e[8];
#pragma unroll
  for (int j = 0; j < 8; ++j) {
    e[j] = (v[j] > -1e29f) ? __expf(v[j] - mx) : 0.f;
    sum += e[j];
  }
#pragma unroll
  for (int o = 32; o; o >>= 1) sum += __shfl_xor(sum, o);
  if (lane == 0) red[4 + wid] = sum;
  __syncthreads();
  sum = red[4] + red[5] + red[6] + red[7];
  float inv = sum > 0.f ? 1.f / sum : 0.f;
  if (act) {
    s16x8 pv;
#pragma unroll
    for (int j = 0; j < 8; ++j) pv[j] = (short)f2bf(e[j] * inv);
    *(s16x8*)(row + t0) = pv;
  }
}

// ---- ctx = P @ Vc  (compacted k; B staged from V-transposed) ---------------
__global__ __launch_bounds__(256, 4) void pv_gemm(
    const unsigned short* __restrict__ P, const unsigned short* __restrict__ Vtc,
    const int* __restrict__ counts, unsigned short* __restrict__ ctx, int b0) {
  int z = blockIdx.z, batch = b0 + z;
  int NT = (counts[batch] + 63) >> 6;
  const unsigned char* Pb = (const unsigned char*)(P + (size_t)z * SEQ * SEQ);
  const unsigned char* Vb = (const unsigned char*)(Vtc + (size_t)batch * HD * SEQ);
  int f = xcd_swz(blockIdx.x + 6 * blockIdx.y, 6 * (SEQ / 128));
  int n0 = (f % 6) * 128, m0 = (f / 6) * 128;
  GEMM_PROLOGUE();
  for (int kt = 0; kt < NT; ++kt) {
    stage_b16(Pb + ((size_t)m0 * SEQ + kt * 64) * 2, SEQ * 2, ldsA, wid, lane);
    stage_b16(Vb + ((size_t)n0 * SEQ + kt * 64) * 2, SEQ * 2, ldsB, wid, lane);
    __syncthreads();
    tile_mfma(ldsA, ldsB, wr, wc, lr, lg, acc);
    __syncthreads();
  }
#pragma unroll
  for (int mi = 0; mi < 4; ++mi)
#pragma unroll
    for (int ni = 0; ni < 4; ++ni) {
      int col = n0 + wc * 64 + ni * 16 + lr;
#pragma unroll
      for (int j = 0; j < 4; ++j) {
        int row = m0 + wr * 64 + mi * 16 + lg * 4 + j;
        ctx[((size_t)batch * SEQ + row) * HD + col] = f2bf(acc[mi][ni][j]);
      }
    }
}

// ---- h = ctx @ Wo + bo + X  (f32 to d_out) ---------------------------------
__global__ __launch_bounds__(256, 4) void outproj_gemm(
    const unsigned short* __restrict__ ctx, const unsigned short* __restrict__ Wto,
    const float* __restrict__ bo, const float* __restrict__ X,
    float* __restrict__ out) {
  int f = xcd_swz(blockIdx.x + 6 * blockIdx.y, 6 * (NBATCH * SEQ / 128));
  int n0 = (f % 6) * 128, m0 = (f / 6) * 128;
  GEMM_PROLOGUE();
  for (int kt = 0; kt < HD / 64; ++kt) {
    stage_b16((const unsigned char*)ctx + ((size_t)m0 * HD + kt * 64) * 2,
              HD * 2, ldsA, wid, lane);
    stage_b16((const unsigned char*)Wto + ((size_t)n0 * HD + kt * 64) * 2,
              HD * 2, ldsB, wid, lane);
    __syncthreads();
    tile_mfma(ldsA, ldsB, wr, wc, lr, lg, acc);
    __syncthreads();
  }
#pragma unroll
  for (int mi = 0; mi < 4; ++mi)
#pragma unroll
    for (int ni = 0; ni < 4; ++ni) {
      int col = n0 + wc * 64 + ni * 16 + lr;
      float bb = bo[col];
#pragma unroll
      for (int j = 0; j < 4; ++j) {
        int row = m0 + wr * 64 + mi * 16 + lg * 4 + j;
        size_t idx = (size_t)row * HD + col;
        out[idx] = acc[mi][ni][j] + bb + X[idx];
      }
    }
}

// ---- LayerNorm in place on d_out: one wave per row -------------------------
__global__ __launch_bounds__(256) void ln_kernel(float* __restrict__ out,
                                                 const float* __restrict__ gamma,
                                                 const float* __restrict__ beta) {
  int tid = threadIdx.x, lane = tid & 63, w = tid >> 6;
  int r = blockIdx.x * 4 + w;
  float* row = out + (size_t)r * HD;
  int c = lane * 4;
  float4 x0 = *(const float4*)(row + c);
  float4 x1 = *(const float4*)(row + 256 + c);
  float4 x2 = *(const float4*)(row + 512 + c);
  float s = x0.x + x0.y + x0.z + x0.w + x1.x + x1.y + x1.z + x1.w +
            x2.x + x2.y + x2.z + x2.w;
  float q = x0.x * x0.x + x0.y * x0.y + x0.z * x0.z + x0.w * x0.w +
            x1.x * x1.x + x1.y * x1.y + x1.z * x1.z + x1.w * x1.w +
            x2.x * x2.x + x2.y * x2.y + x2.z * x2.z + x2.w * x2.w;
#pragma unroll
  for (int o = 32; o; o >>= 1) {
    s += __shfl_xor(s, o);
    q += __shfl_xor(q, o);
  }
  float mu = s * (1.f / 768.f);
  float var = q * (1.f / 768.f) - mu * mu;
  float rstd = rsqrtf(var + 1e-12f);
  float4 g0 = *(const float4*)(gamma + c);
  float4 g1 = *(const float4*)(gamma + 256 + c);
  float4 g2 = *(const float4*)(gamma + 512 + c);
  float4 b0 = *(const float4*)(beta + c);
  float4 b1 = *(const float4*)(beta + 256 + c);
  float4 b2 = *(const float4*)(beta + 512 + c);
  float4 y;
  y.x = (x0.x - mu) * rstd * g0.x + b0.x; y.y = (x0.y - mu) * rstd * g0.y + b0.y;
  y.z = (x0.z - mu) * rstd * g0.z + b0.z; y.w = (x0.w - mu) * rstd * g0.w + b0.w;
  *(float4*)(row + c) = y;
  y.x = (x1.x - mu) * rstd * g1.x + b1.x; y.y = (x1.y - mu) * rstd * g1.y + b1.y;
  y.z = (x1.z - mu) * rstd * g1.z + b1.z; y.w = (x1.w - mu) * rstd * g1.w + b1.w;
  *(float4*)(row + 256 + c) = y;
  y.x = (x2.x - mu) * rstd * g2.x + b2.x; y.y = (x2.y - mu) * rstd * g2.y + b2.y;
  y.z = (x2.z - mu) * rstd * g2.z + b2.z; y.w = (x2.w - mu) * rstd * g2.w + b2.w;
  *(float4*)(row + 512 + c) = y;
}

// ---- host ------------------------------------------------------------------
extern "C" void kernel_launch(void* const* d_in, const int* in_sizes, int n_in,
                              void* d_out, int out_size, void* d_ws, size_t ws_size,
                              hipStream_t stream) {
  const float* X = (const float*)d_in[0];
  const int* mask = (const int*)d_in[1];
  const float* Wq = (const float*)d_in[2];
  const float* bq = (const float*)d_in[3];
  const float* Wk = (const float*)d_in[4];
  const float* bk = (const float*)d_in[5];
  const float* Wv = (const float*)d_in[6];
  const float* bv = (const float*)d_in[7];
  const float* Wo = (const float*)d_in[8];
  const float* bo = (const float*)d_in[9];
  const float* gamma = (const float*)d_in[10];
  const float* beta = (const float*)d_in[11];
  float* out = (float*)d_out;

  char* ws = (char*)d_ws;
  size_t off = 0;
  auto alloc = [&](size_t b) {
    void* p = ws + off;
    off += (b + 255) & ~(size_t)255;
    return p;
  };
  unsigned short* Wt = (unsigned short*)alloc((size_t)4 * HD * HD * 2);
  unsigned short* Xb = (unsigned short*)alloc((size_t)NBATCH * SEQ * HD * 2);
  unsigned short* Q = (unsigned short*)alloc((size_t)NBATCH * SEQ * HD * 2);
  unsigned short* Kc = (unsigned short*)alloc((size_t)NBATCH * SEQ * HD * 2);
  unsigned short* Vtc = (unsigned short*)alloc((size_t)NBATCH * SEQ * HD * 2);
  int* cidx = (int*)alloc((size_t)NBATCH * SEQ * 4);
  int* counts = (int*)alloc(64);
  int nchunk = (ws_size >= off + (size_t)NBATCH * SEQ * SEQ * 2) ? NBATCH : 1;
  unsigned short* Sbuf = (unsigned short*)alloc((size_t)nchunk * SEQ * SEQ * 2);
  unsigned short* ctx = Q;  // Q dead once scores are computed (per batch)

  // zero compacted K/V (adjacent allocations, 2*24MB, 16B/thread)
  zero_fill<<<(2 * NBATCH * SEQ * HD) / (256 * 8), 256, 0, stream>>>((s16x8*)Kc);
  compact_mask<<<NBATCH, 256, 0, stream>>>(mask, cidx, counts);
  prep_weights<<<dim3(HD / 64, HD / 64, 4), 256, 0, stream>>>(Wq, Wk, Wv, Wo, Wt);
  prep_x<<<(NBATCH * SEQ * HD) / (256 * 8), 256, 0, stream>>>(X, Xb);
  qkv_gemm<<<dim3(HD / 128, NBATCH * SEQ / 128, 3), 256, 0, stream>>>(
      Xb, Wt, bq, bk, bv, cidx, Q, Kc, Vtc);
  for (int b0 = 0; b0 < NBATCH; b0 += nchunk) {
    scores_gemm<<<dim3(SEQ / 128, SEQ / 128, nchunk), 256, 0, stream>>>(
        Q, Kc, counts, Sbuf, b0);
    softmax_kernel<<<dim3(SEQ, nchunk), 256, 0, stream>>>(Sbuf, counts, b0);
    pv_gemm<<<dim3(HD / 128, SEQ / 128, nchunk), 256, 0, stream>>>(
        Sbuf, Vtc, counts, ctx, b0);
  }
  outproj_gemm<<<dim3(HD / 128, NBATCH * SEQ / 128), 256, 0, stream>>>(
      ctx, Wt + (size_t)3 * HD * HD, bo, X, out);
  ln_kernel<<<NBATCH * SEQ / 4, 256, 0, stream>>>(out, gamma, beta);
}

// Round 6
// 297.337 us; speedup vs baseline: 1.3563x; 1.1668x over previous
//
#include <hip/hip_runtime.h>

#define SEQ 2048
#define HD 768
#define NBATCH 8

typedef __attribute__((ext_vector_type(4))) float f32x4;
typedef __attribute__((ext_vector_type(8))) short s16x8;

__device__ __forceinline__ unsigned short f2bf(float f) {
  unsigned int u = __builtin_bit_cast(unsigned int, f);
  u += 0x7fffu + ((u >> 16) & 1u);
  return (unsigned short)(u >> 16);
}
__device__ __forceinline__ float bf2f(unsigned short h) {
  unsigned int u = ((unsigned int)h) << 16;
  return __builtin_bit_cast(float, u);
}

typedef const __attribute__((address_space(1))) void gas_void;
typedef __attribute__((address_space(3))) void las_void;

__device__ __forceinline__ void gload_lds16(const void* g, void* l) {
  __builtin_amdgcn_global_load_lds((gas_void*)g, (las_void*)l, 16, 0, 0);
}

// bijective XCD-chunk swizzle; requires nwg % 8 == 0
__device__ __forceinline__ int xcd_swz(int f, int nwg) {
  int q = nwg >> 3;
  return (f & 7) * q + (f >> 3);
}

// ---- GEMM building blocks (verified R3 128x128 structure) ------------------
// LDS tile: 128 rows x 64 bf16 cols (128 B/row), XOR-swizzled:
//   phys = row*128 + (cb ^ ((row&7)<<4)); staging pre-swizzles the global
//   SOURCE column so global_load_lds' linear dest lands correctly (rule #21).

__device__ __forceinline__ void stage_b16(const unsigned char* g, size_t ldgB,
                                          unsigned char* lds, int wid, int lane) {
#pragma unroll
  for (int c = 0; c < 4; ++c) {
    int f0 = (wid * 4 + c) * 1024;                  // wave-uniform LDS base
    int row = (f0 >> 7) + (lane >> 3);              // 8 rows per 1024B call
    int cb = (((lane & 7) ^ (lane >> 3)) & 7) << 4; // inverse-swizzled src col
    gload_lds16(g + (size_t)row * ldgB + cb, lds + f0);
  }
}

// gathered A-staging: per-lane global SOURCE rows from a gather map (rows
// preloaded once per block into gr); LDS dest stays linear (rule #21 holds).
__device__ __forceinline__ void stage_gather(const unsigned char* gb, int4 gr,
                                             int ktB, unsigned char* lds,
                                             int wid, int lane) {
  int cb = (((lane & 7) ^ (lane >> 3)) & 7) << 4;
  int rows[4] = {gr.x, gr.y, gr.z, gr.w};
#pragma unroll
  for (int c = 0; c < 4; ++c)
    gload_lds16(gb + (size_t)rows[c] * (HD * 2) + ktB + cb,
                lds + (wid * 4 + c) * 1024);
}

// 4 waves, wave (wr,wc) owns 64x64; 4x4 frags of 16x16, BK=64 (2 k-substeps)
__device__ __forceinline__ void tile_mfma(const unsigned char* ldsA,
                                          const unsigned char* ldsB,
                                          int wr, int wc, int lr, int lg,
                                          f32x4 acc[4][4]) {
  int aswz = (lr & 7) << 4;
#pragma unroll
  for (int ks = 0; ks < 2; ++ks) {
    int cb = (ks * 64 + lg * 16) ^ aswz;
    s16x8 af[4], bfv[4];
#pragma unroll
    for (int i = 0; i < 4; ++i)
      af[i] = *(const s16x8*)(ldsA + (wr * 64 + i * 16 + lr) * 128 + cb);
#pragma unroll
    for (int i = 0; i < 4; ++i)
      bfv[i] = *(const s16x8*)(ldsB + (wc * 64 + i * 16 + lr) * 128 + cb);
#pragma unroll
    for (int mi = 0; mi < 4; ++mi)
#pragma unroll
      for (int ni = 0; ni < 4; ++ni)
        acc[mi][ni] = __builtin_amdgcn_mfma_f32_16x16x32_bf16(
            af[mi], bfv[ni], acc[mi][ni], 0, 0, 0);
  }
}

#define GEMM_PROLOGUE()                                              \
  __shared__ unsigned char lds[32768];                               \
  unsigned char* ldsA = lds;                                         \
  unsigned char* ldsB = lds + 16384;                                 \
  int lr = lane & 15, lg = lane >> 4, wr = wid >> 1, wc = wid & 1;   \
  f32x4 acc[4][4];                                                   \
  {                                                                  \
    f32x4 zz = {0.f, 0.f, 0.f, 0.f};                                 \
    for (int a_ = 0; a_ < 4; ++a_)                                   \
      for (int b_ = 0; b_ < 4; ++b_) acc[a_][b_] = zz;               \
  }

// ---- mask compaction: gidx[b][slot] = source seq idx; counts[b] = #kept ----
__global__ __launch_bounds__(256) void compact_mask(const int* __restrict__ mask,
                                                    int* __restrict__ gidx,
                                                    int* __restrict__ counts) {
  int b = blockIdx.x;
  const int* m = mask + (size_t)b * SEQ;
  int* gi = gidx + (size_t)b * SEQ;
  int tid = threadIdx.x, lane = tid & 63, wid = tid >> 6;
  int t0 = tid * 8;
  int4 a = *(const int4*)(m + t0);
  int4 c = *(const int4*)(m + t0 + 4);
  int mk[8] = {a.x, a.y, a.z, a.w, c.x, c.y, c.z, c.w};
  // zero-init gather map (pad slots -> row 0, finite values)
#pragma unroll
  for (int j = 0; j < 8; ++j) gi[t0 + j] = 0;
  int psum[8], s = 0;
#pragma unroll
  for (int j = 0; j < 8; ++j) {
    psum[j] = s;
    s += (mk[j] != 0);
  }
  int incl = s;
  for (int o = 1; o < 64; o <<= 1) {
    int t = __shfl_up(incl, o);
    if (lane >= o) incl += t;
  }
  int wexcl = incl - s;
  __shared__ int wtot[4];
  if (lane == 63) wtot[wid] = incl;
  __syncthreads();
  int woff = 0;
#pragma unroll
  for (int w2 = 0; w2 < 4; ++w2)
    if (w2 < wid) woff += wtot[w2];
  int base = woff + wexcl;
#pragma unroll
  for (int j = 0; j < 8; ++j)
    if (mk[j]) gi[base + psum[j]] = t0 + j;
  if (tid == 255) counts[b] = woff + incl;
}

// ---- prep: LDS-tiled weight transpose+convert  Wt[n][k] = bf16(W[k][n]) ----
__global__ __launch_bounds__(256) void prep_weights(
    const float* __restrict__ Wq, const float* __restrict__ Wk,
    const float* __restrict__ Wv, const float* __restrict__ Wo,
    unsigned short* __restrict__ Wt) {
  int mat = blockIdx.z;
  const float* W = mat == 0 ? Wq : mat == 1 ? Wk : mat == 2 ? Wv : Wo;
  unsigned short* dst = Wt + (size_t)mat * HD * HD;
  int n0 = blockIdx.x * 64, k0 = blockIdx.y * 64;
  __shared__ float t[64][65];
  int tid = threadIdx.x;
  int c4 = (tid & 15) * 4, r = tid >> 4;
#pragma unroll
  for (int p = 0; p < 4; ++p) {
    int kr = r + p * 16;
    float4 v = *(const float4*)(W + (size_t)(k0 + kr) * HD + n0 + c4);
    t[kr][c4 + 0] = v.x; t[kr][c4 + 1] = v.y;
    t[kr][c4 + 2] = v.z; t[kr][c4 + 3] = v.w;
  }
  __syncthreads();
#pragma unroll
  for (int p = 0; p < 4; ++p) {
    int nr = r + p * 16;
    ushort4 o;
    o.x = f2bf(t[c4 + 0][nr]); o.y = f2bf(t[c4 + 1][nr]);
    o.z = f2bf(t[c4 + 2][nr]); o.w = f2bf(t[c4 + 3][nr]);
    *(ushort4*)(dst + (size_t)(n0 + nr) * HD + k0 + c4) = o;
  }
}

// ---- prep: X f32 -> bf16 ----------------------------------------------------
__global__ __launch_bounds__(256) void prep_x(const float* __restrict__ X,
                                              unsigned short* __restrict__ Xb) {
  size_t i = ((size_t)blockIdx.x * 256 + threadIdx.x) * 8;
  const float4* gp = (const float4*)(X + i);
  float4 a = gp[0], b = gp[1];
  s16x8 v;
  v[0] = (short)f2bf(a.x); v[1] = (short)f2bf(a.y);
  v[2] = (short)f2bf(a.z); v[3] = (short)f2bf(a.w);
  v[4] = (short)f2bf(b.x); v[5] = (short)f2bf(b.y);
  v[6] = (short)f2bf(b.z); v[7] = (short)f2bf(b.w);
  *(s16x8*)(Xb + i) = v;
}

// ---- QKV projection (z: 0=Q full, 1=K compacted-rows, 2=Vt compacted) ------
__global__ __launch_bounds__(256, 4) void qkv_gemm(
    const unsigned short* __restrict__ Xb, const unsigned short* __restrict__ Wt,
    const float* __restrict__ bq, const float* __restrict__ bk,
    const float* __restrict__ bv, const int* __restrict__ gidx,
    const int* __restrict__ counts, unsigned short* __restrict__ Q,
    unsigned short* __restrict__ Kc, unsigned short* __restrict__ Vtc) {
  int which = blockIdx.z;
  const unsigned short* W = Wt + (size_t)which * HD * HD;
  const float* bias = which == 0 ? bq : which == 1 ? bk : bv;
  int f = xcd_swz(blockIdx.x + 6 * blockIdx.y, 6 * (NBATCH * SEQ / 128));
  int n0 = (f % 6) * 128, mt = f / 6;
  int b = mt >> 4, mloc = (mt & 15) * 128;
  if (which > 0 && mloc >= counts[b]) return;  // block-uniform early exit
  int tid = threadIdx.x, lane = tid & 63, wid = tid >> 6;
  GEMM_PROLOGUE();
  const unsigned char* Abase;
  int4 gr = {0, 0, 0, 0};
  if (which > 0) {
    const int* gix = gidx + (size_t)b * SEQ + mloc;
    int rb = wid * 32 + (lane >> 3);  // rows (wid*4+c)*8 + lane>>3, c=0..3
    gr.x = gix[rb]; gr.y = gix[rb + 8]; gr.z = gix[rb + 16]; gr.w = gix[rb + 24];
    Abase = (const unsigned char*)(Xb + (size_t)b * SEQ * HD);
  } else {
    Abase = (const unsigned char*)(Xb + (size_t)mt * 128 * HD);
  }
  for (int kt = 0; kt < HD / 64; ++kt) {
    if (which > 0)
      stage_gather(Abase, gr, kt * 128, ldsA, wid, lane);
    else
      stage_b16(Abase + kt * 128, HD * 2, ldsA, wid, lane);
    stage_b16((const unsigned char*)W + ((size_t)n0 * HD + kt * 64) * 2,
              HD * 2, ldsB, wid, lane);
    __syncthreads();
    tile_mfma(ldsA, ldsB, wr, wc, lr, lg, acc);
    __syncthreads();
  }
  if (which == 0) {
#pragma unroll
    for (int mi = 0; mi < 4; ++mi)
#pragma unroll
      for (int ni = 0; ni < 4; ++ni) {
        int col = n0 + wc * 64 + ni * 16 + lr;
        float bb = bias[col];
#pragma unroll
        for (int j = 0; j < 4; ++j) {
          int row = mt * 128 + wr * 64 + mi * 16 + lg * 4 + j;
          Q[(size_t)row * HD + col] = f2bf(acc[mi][ni][j] + bb);
        }
      }
  } else if (which == 1) {
#pragma unroll
    for (int mi = 0; mi < 4; ++mi)
#pragma unroll
      for (int ni = 0; ni < 4; ++ni) {
        int col = n0 + wc * 64 + ni * 16 + lr;
        float bb = bias[col];
#pragma unroll
        for (int j = 0; j < 4; ++j) {
          int slot = mloc + wr * 64 + mi * 16 + lg * 4 + j;
          Kc[((size_t)b * SEQ + slot) * HD + col] = f2bf(acc[mi][ni][j] + bb);
        }
      }
  } else {
#pragma unroll
    for (int mi = 0; mi < 4; ++mi)
#pragma unroll
      for (int ni = 0; ni < 4; ++ni) {
        int col = n0 + wc * 64 + ni * 16 + lr;
        float bb = bias[col];
#pragma unroll
        for (int j = 0; j < 4; ++j) {
          int slot = mloc + wr * 64 + mi * 16 + lg * 4 + j;
          Vtc[(size_t)b * HD * SEQ + (size_t)col * SEQ + slot] =
              f2bf(acc[mi][ni][j] + bb);
        }
      }
  }
}

// ---- scores = scale * Q @ Kc^T  (compacted key dim, bf16 out) --------------
__global__ __launch_bounds__(256, 4) void scores_gemm(
    const unsigned short* __restrict__ Q, const unsigned short* __restrict__ Kc,
    const int* __restrict__ counts, unsigned short* __restrict__ S, int b0) {
  int z = blockIdx.z, batch = b0 + z;
  int count = counts[batch];
  int f = xcd_swz(blockIdx.x + 16 * blockIdx.y, 256);
  int n0 = (f % 16) * 128, m0 = (f / 16) * 128;
  if (n0 >= count) return;  // whole block masked out (uniform exit)
  const unsigned char* Qb = (const unsigned char*)(Q + (size_t)batch * SEQ * HD);
  const unsigned char* Kb = (const unsigned char*)(Kc + (size_t)batch * SEQ * HD);
  unsigned short* Sout = S + (size_t)z * SEQ * SEQ;
  int tid = threadIdx.x, lane = tid & 63, wid = tid >> 6;
  GEMM_PROLOGUE();
  for (int kt = 0; kt < HD / 64; ++kt) {
    stage_b16(Qb + ((size_t)m0 * HD + kt * 64) * 2, HD * 2, ldsA, wid, lane);
    stage_b16(Kb + ((size_t)n0 * HD + kt * 64) * 2, HD * 2, ldsB, wid, lane);
    __syncthreads();
    tile_mfma(ldsA, ldsB, wr, wc, lr, lg, acc);
    __syncthreads();
  }
  const float scale = 0.036084391824351615f;  // 1/sqrt(768)
#pragma unroll
  for (int mi = 0; mi < 4; ++mi)
#pragma unroll
    for (int ni = 0; ni < 4; ++ni) {
      int col = n0 + wc * 64 + ni * 16 + lr;
#pragma unroll
      for (int j = 0; j < 4; ++j) {
        int row = m0 + wr * 64 + mi * 16 + lg * 4 + j;
        Sout[(size_t)row * SEQ + col] = f2bf(acc[mi][ni][j] * scale);
      }
    }
}

// ---- softmax over compacted key dim, in place on S -------------------------
__global__ __launch_bounds__(256) void softmax_kernel(
    unsigned short* __restrict__ S, const int* __restrict__ counts, int b0) {
  int z = blockIdx.y, batch = b0 + z;
  int count = counts[batch];
  int nt64 = ((count + 63) >> 6) << 6;  // width pv will consume
  int r = blockIdx.x;
  unsigned short* row = S + ((size_t)z * SEQ + r) * SEQ;
  int tid = threadIdx.x, lane = tid & 63, wid = tid >> 6;
  int t0 = tid * 8;
  bool act = t0 < nt64;
  s16x8 sv = {0, 0, 0, 0, 0, 0, 0, 0};
  if (act) sv = *(const s16x8*)(row + t0);
  float v[8];
  float mx = -1e30f;
#pragma unroll
  for (int j = 0; j < 8; ++j) {
    float x = bf2f((unsigned short)sv[j]);
    bool keep = act && (t0 + j < count);
    v[j] = keep ? x : -1e30f;
    mx = fmaxf(mx, v[j]);
  }
#pragma unroll
  for (int o = 32; o; o >>= 1) mx = fmaxf(mx, __shfl_xor(mx, o));
  __shared__ float red[8];
  if (lane == 0) red[wid] = mx;
  __syncthreads();
  mx = fmaxf(fmaxf(red[0], red[1]), fmaxf(red[2], red[3]));
  float sum = 0.f;
  float e[8];
#pragma unroll
  for (int j = 0; j < 8; ++j) {
    e[j] = (v[j] > -1e29f) ? __expf(v[j] - mx) : 0.f;
    sum += e[j];
  }
#pragma unroll
  for (int o = 32; o; o >>= 1) sum += __shfl_xor(sum, o);
  if (lane == 0) red[4 + wid] = sum;
  __syncthreads();
  sum = red[4] + red[5] + red[6] + red[7];
  float inv = sum > 0.f ? 1.f / sum : 0.f;
  if (act) {
    s16x8 pv;
#pragma unroll
    for (int j = 0; j < 8; ++j) pv[j] = (short)f2bf(e[j] * inv);
    *(s16x8*)(row + t0) = pv;
  }
}

// ---- ctx = P @ Vc  (compacted k; B staged from V-transposed) ---------------
__global__ __launch_bounds__(256, 4) void pv_gemm(
    const unsigned short* __restrict__ P, const unsigned short* __restrict__ Vtc,
    const int* __restrict__ counts, unsigned short* __restrict__ ctx, int b0) {
  int z = blockIdx.z, batch = b0 + z;
  int NT = (counts[batch] + 63) >> 6;
  const unsigned char* Pb = (const unsigned char*)(P + (size_t)z * SEQ * SEQ);
  const unsigned char* Vb = (const unsigned char*)(Vtc + (size_t)batch * HD * SEQ);
  int f = xcd_swz(blockIdx.x + 6 * blockIdx.y, 6 * (SEQ / 128));
  int n0 = (f % 6) * 128, m0 = (f / 6) * 128;
  int tid = threadIdx.x, lane = tid & 63, wid = tid >> 6;
  GEMM_PROLOGUE();
  for (int kt = 0; kt < NT; ++kt) {
    stage_b16(Pb + ((size_t)m0 * SEQ + kt * 64) * 2, SEQ * 2, ldsA, wid, lane);
    stage_b16(Vb + ((size_t)n0 * SEQ + kt * 64) * 2, SEQ * 2, ldsB, wid, lane);
    __syncthreads();
    tile_mfma(ldsA, ldsB, wr, wc, lr, lg, acc);
    __syncthreads();
  }
#pragma unroll
  for (int mi = 0; mi < 4; ++mi)
#pragma unroll
    for (int ni = 0; ni < 4; ++ni) {
      int col = n0 + wc * 64 + ni * 16 + lr;
#pragma unroll
      for (int j = 0; j < 4; ++j) {
        int row = m0 + wr * 64 + mi * 16 + lg * 4 + j;
        ctx[((size_t)batch * SEQ + row) * HD + col] = f2bf(acc[mi][ni][j]);
      }
    }
}

// ---- h = ctx @ Wo + bo + X  (f32 to d_out) ---------------------------------
__global__ __launch_bounds__(256, 4) void outproj_gemm(
    const unsigned short* __restrict__ ctx, const unsigned short* __restrict__ Wto,
    const float* __restrict__ bo, const float* __restrict__ X,
    float* __restrict__ out) {
  int f = xcd_swz(blockIdx.x + 6 * blockIdx.y, 6 * (NBATCH * SEQ / 128));
  int n0 = (f % 6) * 128, m0 = (f / 6) * 128;
  int tid = threadIdx.x, lane = tid & 63, wid = tid >> 6;
  GEMM_PROLOGUE();
  for (int kt = 0; kt < HD / 64; ++kt) {
    stage_b16((const unsigned char*)ctx + ((size_t)m0 * HD + kt * 64) * 2,
              HD * 2, ldsA, wid, lane);
    stage_b16((const unsigned char*)Wto + ((size_t)n0 * HD + kt * 64) * 2,
              HD * 2, ldsB, wid, lane);
    __syncthreads();
    tile_mfma(ldsA, ldsB, wr, wc, lr, lg, acc);
    __syncthreads();
  }
#pragma unroll
  for (int mi = 0; mi < 4; ++mi)
#pragma unroll
    for (int ni = 0; ni < 4; ++ni) {
      int col = n0 + wc * 64 + ni * 16 + lr;
      float bb = bo[col];
#pragma unroll
      for (int j = 0; j < 4; ++j) {
        int row = m0 + wr * 64 + mi * 16 + lg * 4 + j;
        size_t idx = (size_t)row * HD + col;
        out[idx] = acc[mi][ni][j] + bb + X[idx];
      }
    }
}

// ---- LayerNorm in place on d_out: one wave per row -------------------------
__global__ __launch_bounds__(256) void ln_kernel(float* __restrict__ out,
                                                 const float* __restrict__ gamma,
                                                 const float* __restrict__ beta) {
  int tid = threadIdx.x, lane = tid & 63, w = tid >> 6;
  int r = blockIdx.x * 4 + w;
  float* row = out + (size_t)r * HD;
  int c = lane * 4;
  float4 x0 = *(const float4*)(row + c);
  float4 x1 = *(const float4*)(row + 256 + c);
  float4 x2 = *(const float4*)(row + 512 + c);
  float s = x0.x + x0.y + x0.z + x0.w + x1.x + x1.y + x1.z + x1.w +
            x2.x + x2.y + x2.z + x2.w;
  float q = x0.x * x0.x + x0.y * x0.y + x0.z * x0.z + x0.w * x0.w +
            x1.x * x1.x + x1.y * x1.y + x1.z * x1.z + x1.w * x1.w +
            x2.x * x2.x + x2.y * x2.y + x2.z * x2.z + x2.w * x2.w;
#pragma unroll
  for (int o = 32; o; o >>= 1) {
    s += __shfl_xor(s, o);
    q += __shfl_xor(q, o);
  }
  float mu = s * (1.f / 768.f);
  float var = q * (1.f / 768.f) - mu * mu;
  float rstd = rsqrtf(var + 1e-12f);
  float4 g0 = *(const float4*)(gamma + c);
  float4 g1 = *(const float4*)(gamma + 256 + c);
  float4 g2 = *(const float4*)(gamma + 512 + c);
  float4 b0 = *(const float4*)(beta + c);
  float4 b1 = *(const float4*)(beta + 256 + c);
  float4 b2 = *(const float4*)(beta + 512 + c);
  float4 y;
  y.x = (x0.x - mu) * rstd * g0.x + b0.x; y.y = (x0.y - mu) * rstd * g0.y + b0.y;
  y.z = (x0.z - mu) * rstd * g0.z + b0.z; y.w = (x0.w - mu) * rstd * g0.w + b0.w;
  *(float4*)(row + c) = y;
  y.x = (x1.x - mu) * rstd * g1.x + b1.x; y.y = (x1.y - mu) * rstd * g1.y + b1.y;
  y.z = (x1.z - mu) * rstd * g1.z + b1.z; y.w = (x1.w - mu) * rstd * g1.w + b1.w;
  *(float4*)(row + 256 + c) = y;
  y.x = (x2.x - mu) * rstd * g2.x + b2.x; y.y = (x2.y - mu) * rstd * g2.y + b2.y;
  y.z = (x2.z - mu) * rstd * g2.z + b2.z; y.w = (x2.w - mu) * rstd * g2.w + b2.w;
  *(float4*)(row + 512 + c) = y;
}

// ---- host ------------------------------------------------------------------
extern "C" void kernel_launch(void* const* d_in, const int* in_sizes, int n_in,
                              void* d_out, int out_size, void* d_ws, size_t ws_size,
                              hipStream_t stream) {
  const float* X = (const float*)d_in[0];
  const int* mask = (const int*)d_in[1];
  const float* Wq = (const float*)d_in[2];
  const float* bq = (const float*)d_in[3];
  const float* Wk = (const float*)d_in[4];
  const float* bk = (const float*)d_in[5];
  const float* Wv = (const float*)d_in[6];
  const float* bv = (const float*)d_in[7];
  const float* Wo = (const float*)d_in[8];
  const float* bo = (const float*)d_in[9];
  const float* gamma = (const float*)d_in[10];
  const float* beta = (const float*)d_in[11];
  float* out = (float*)d_out;

  char* ws = (char*)d_ws;
  size_t off = 0;
  auto alloc = [&](size_t b) {
    void* p = ws + off;
    off += (b + 255) & ~(size_t)255;
    return p;
  };
  unsigned short* Wt = (unsigned short*)alloc((size_t)4 * HD * HD * 2);
  unsigned short* Xb = (unsigned short*)alloc((size_t)NBATCH * SEQ * HD * 2);
  unsigned short* Q = (unsigned short*)alloc((size_t)NBATCH * SEQ * HD * 2);
  unsigned short* Kc = (unsigned short*)alloc((size_t)NBATCH * SEQ * HD * 2);
  unsigned short* Vtc = (unsigned short*)alloc((size_t)NBATCH * SEQ * HD * 2);
  int* gidx = (int*)alloc((size_t)NBATCH * SEQ * 4);
  int* counts = (int*)alloc(64);
  // largest chunking that fits the workspace: 8 -> 4 -> 2 -> 1
  int nchunk = 1;
  for (int c = NBATCH; c >= 1; c >>= 1)
    if (ws_size >= off + (size_t)c * SEQ * SEQ * 2) { nchunk = c; break; }
  unsigned short* Sbuf = (unsigned short*)alloc((size_t)nchunk * SEQ * SEQ * 2);
  unsigned short* ctx = Q;  // Q dead once scores are computed (per chunk)

  compact_mask<<<NBATCH, 256, 0, stream>>>(mask, gidx, counts);
  prep_weights<<<dim3(HD / 64, HD / 64, 4), 256, 0, stream>>>(Wq, Wk, Wv, Wo, Wt);
  prep_x<<<(NBATCH * SEQ * HD) / (256 * 8), 256, 0, stream>>>(X, Xb);
  qkv_gemm<<<dim3(HD / 128, NBATCH * SEQ / 128, 3), 256, 0, stream>>>(
      Xb, Wt, bq, bk, bv, gidx, counts, Q, Kc, Vtc);
  for (int b0 = 0; b0 < NBATCH; b0 += nchunk) {
    scores_gemm<<<dim3(SEQ / 128, SEQ / 128, nchunk), 256, 0, stream>>>(
        Q, Kc, counts, Sbuf, b0);
    softmax_kernel<<<dim3(SEQ, nchunk), 256, 0, stream>>>(Sbuf, counts, b0);
    pv_gemm<<<dim3(HD / 128, SEQ / 128, nchunk), 256, 0, stream>>>(
        Sbuf, Vtc, counts, ctx, b0);
  }
  outproj_gemm<<<dim3(HD / 128, NBATCH * SEQ / 128), 256, 0, stream>>>(
      ctx, Wt + (size_t)3 * HD * HD, bo, X, out);
  ln_kernel<<<NBATCH * SEQ / 4, 256, 0, stream>>>(out, gamma, beta);
}